// Round 2
// baseline (288.834 us; speedup 1.0000x reference)
//
#include <hip/hip_runtime.h>
#include <hip/hip_bf16.h>
#include <cstdint>
#include <cstddef>

// ---------------------------------------------------------------------------
// LRU layer (fp32 I/O): h = scan( (x W_in^T + b_in)*gamma, lambda, mask )
//                       out = LN( Re(h W_out^T + b_out) + x )
// B=8 L=2048 D=512 H=1024. Inputs/outputs fp32; GEMMs run bf16 MFMA with
// fp32 accumulation; scan state fp32, h stored bf16.
// ---------------------------------------------------------------------------

typedef unsigned short u16;
typedef __attribute__((ext_vector_type(8))) short bf16x8;   // 8 bf16 = 4 VGPRs
typedef __attribute__((ext_vector_type(4))) float f32x4;

#define B_    8
#define L_    2048
#define D_    512
#define H_    1024
#define M_    (B_ * L_)      // 16384 rows
#define SEG_  32             // scan segments
#define T_    (L_ / SEG_)    // 64 steps/segment

__device__ __forceinline__ float b2f(u16 u) {
  union { unsigned int i; float f; } v; v.i = ((unsigned int)u) << 16; return v.f;
}
__device__ __forceinline__ u16 f2b(float f) {
  union { float f; unsigned int i; } v; v.f = f;
  unsigned int x = v.i;
  return (u16)((x + 0x7fffu + ((x >> 16) & 1u)) >> 16);   // RNE
}

// async global->LDS, 16B per lane. LDS dst must be uniform-base + lane*16.
__device__ __forceinline__ void gl2lds16(const void* g, void* l) {
  __builtin_amdgcn_global_load_lds(
      (const __attribute__((address_space(1))) void*)g,
      (__attribute__((address_space(3))) void*)l, 16, 0, 0);
}

// XOR swizzle of the 4 16B-chunks in a 32-wide K row: 2-way LDS aliasing max.
__device__ __forceinline__ int ksw(int row, int kc) {
  return (kc ^ (row & 3) ^ ((row >> 2) & 3)) & 3;
}

// ---------------------------------------------------------------------------
// fp32 -> bf16 elementwise, 4 elems/thread (n4 = n/4 float4 groups)
// ---------------------------------------------------------------------------
__global__ __launch_bounds__(256) void conv_f32_bf16(
    const float* __restrict__ in, u16* __restrict__ out, int n4)
{
  int i = blockIdx.x * 256 + threadIdx.x;
  if (i < n4) {
    float4 v = ((const float4*)in)[i];
    ushort4 o;
    o.x = f2b(v.x); o.y = f2b(v.y); o.z = f2b(v.z); o.w = f2b(v.w);
    ((ushort4*)out)[i] = o;
  }
}

// Wcat[d][c] = W_out_re[d][c]; Wcat[d][1024+c] = -W_out_im[d][c]  (bf16)
__global__ __launch_bounds__(256) void prep_wcat(
    const float* __restrict__ wre, const float* __restrict__ wim,
    u16* __restrict__ wcat)
{
  int i = blockIdx.x * 256 + threadIdx.x;        // 0 .. 512*1024-1
  int d = i >> 10, c = i & 1023;
  wcat[(size_t)d * 2048 + c]        = f2b(wre[i]);
  wcat[(size_t)d * 2048 + 1024 + c] = f2b(-wim[i]);
}

// ---------------------------------------------------------------------------
// gemm_bt: C(M x N) = A(M x K) * B(N x K)^T, 128x128 tile, 4 waves 2x2,
// 16x16x32 bf16 MFMA, BK=32, global_load_lds staging (m97 structure).
// MODE 0: out bf16; val=(acc + bias[n]) * exp(params[2048 + (n&1023)]),
//         bias = n<1024 ? b_in_re[n] : b_in_im[n-1024].
// MODE 1: out fp32; val=acc + p0[n].
// ---------------------------------------------------------------------------
template <int MODE>
__global__ __launch_bounds__(256, 2) void gemm_bt(
    const u16* __restrict__ A, const u16* __restrict__ Bp, int K,
    void* __restrict__ outp, int ldc,
    const float* __restrict__ p0, const float* __restrict__ p1,
    const float* __restrict__ p2)
{
  __shared__ __align__(16) u16 sA[128 * 32];
  __shared__ __align__(16) u16 sB[128 * 32];

  const int tid  = threadIdx.x;
  const int lane = tid & 63;
  const int wave = tid >> 6;
  const int wm = wave >> 1, wn = wave & 1;           // 2x2 wave grid, 64x64 each
  const int m0 = blockIdx.y * 128;
  const int n0 = blockIdx.x * 128;

  f32x4 acc[4][4];
#pragma unroll
  for (int i = 0; i < 4; ++i)
#pragma unroll
    for (int j = 0; j < 4; ++j) { f32x4 z = {0.f, 0.f, 0.f, 0.f}; acc[i][j] = z; }

  const int q = lane >> 4;       // quad 0..3 -> k-offset q*8
  const int r = lane & 15;       // m (A) / n (B) index within 16

  for (int k0 = 0; k0 < K; k0 += 32) {
    // stage A,B tiles: 512 chunks of 16B each, 2 per thread per matrix
#pragma unroll
    for (int it = 0; it < 2; ++it) {
      int ci  = it * 256 + tid;          // LDS slot; dst = uniform + lane*16
      int row = ci >> 2;
      int kc  = ksw(row, ci & 3);        // swizzled source chunk
      gl2lds16(A  + (size_t)(m0 + row) * K + k0 + kc * 8, &sA[ci * 8]);
      gl2lds16(Bp + (size_t)(n0 + row) * K + k0 + kc * 8, &sB[ci * 8]);
    }
    __syncthreads();   // compiler emits vmcnt(0) drain before s_barrier

    bf16x8 af[4], bfv[4];
#pragma unroll
    for (int mt = 0; mt < 4; ++mt) {
      int arow = wm * 64 + mt * 16 + r;
      int slot = (arow << 2) | ksw(arow, q);
      af[mt] = *(const bf16x8*)&sA[slot * 8];
    }
#pragma unroll
    for (int nt = 0; nt < 4; ++nt) {
      int brow = wn * 64 + nt * 16 + r;
      int slot = (brow << 2) | ksw(brow, q);
      bfv[nt] = *(const bf16x8*)&sB[slot * 8];
    }
#pragma unroll
    for (int mt = 0; mt < 4; ++mt)
#pragma unroll
      for (int nt = 0; nt < 4; ++nt)
        acc[mt][nt] = __builtin_amdgcn_mfma_f32_16x16x32_bf16(
            af[mt], bfv[nt], acc[mt][nt], 0, 0, 0);
    __syncthreads();
  }

  // epilogue. D layout (m89-verified): col=lane&15 (n), row=q*4+i (m)
#pragma unroll
  for (int nt = 0; nt < 4; ++nt) {
    const int ng = n0 + wn * 64 + nt * 16 + r;
    float bias, gam = 1.f;
    if (MODE == 0) {
      bias = (ng < 1024) ? p0[ng] : p1[ng - 1024];
      gam  = expf(p2[2 * H_ + (ng & (H_ - 1))]);   // gamma = exp(gamma_log)
    } else {
      bias = p0[ng];
    }
#pragma unroll
    for (int mt = 0; mt < 4; ++mt) {
      const int mg = m0 + wm * 64 + mt * 16 + q * 4;
#pragma unroll
      for (int i = 0; i < 4; ++i) {
        float v = acc[mt][nt][i] + bias;
        if (MODE == 0)
          ((u16*)outp)[(size_t)(mg + i) * ldc + ng] = f2b(v * gam);
        else
          ((float*)outp)[(size_t)(mg + i) * ldc + ng] = v;
      }
    }
  }
}

// ---------------------------------------------------------------------------
// Scan pass 1: per (b, segment) block, 256 threads x 4 channels, local
// inclusive scan in fp32 regs, h updated in place (bf16), store segment-final
// state + mask product.  Recurrence: h_t = x_t + lambda * m[t-1] * h_{t-1}.
// ---------------------------------------------------------------------------
__global__ __launch_bounds__(256) void scan_local(
    u16* __restrict__ h, const float* __restrict__ mask,
    const float* __restrict__ params, float2* __restrict__ segfin,
    float* __restrict__ prodm)
{
  const int s = blockIdx.x, b = blockIdx.y;
  const int c4 = threadIdx.x * 4;
  float lr[4], li[4];
#pragma unroll
  for (int j = 0; j < 4; ++j) {
    int c = c4 + j;
    float nu = expf(params[c]);
    float th = expf(params[H_ + c]);
    float mg = expf(-nu);
    lr[j] = mg * cosf(th);
    li[j] = mg * sinf(th);
  }
  const int t0 = s * T_;
  u16* p = h + (size_t)(b * L_ + t0) * (2 * H_) + c4;
  const float* mp = mask + b * L_ + t0;
  float sr[4] = {0, 0, 0, 0}, si[4] = {0, 0, 0, 0};
  float pm = 1.f;
  ushort4 cre = *(const ushort4*)p;
  ushort4 cim = *(const ushort4*)(p + H_);
  for (int i = 0; i < T_; ++i) {
    ushort4 nre = cre, nim = cim;
    if (i + 1 < T_) {                       // prefetch next row before store
      nre = *(const ushort4*)(p + 2 * H_);
      nim = *(const ushort4*)(p + 2 * H_ + H_);
    }
    float fac = (t0 + i == 0) ? 0.f : mp[i - 1];
    pm *= fac;
    u16 rr[4], ii[4], orr[4], oii[4];
    *(ushort4*)rr = cre; *(ushort4*)ii = cim;
#pragma unroll
    for (int j = 0; j < 4; ++j) {
      float ar = fac * sr[j], ai = fac * si[j];
      float nr2 = b2f(rr[j]) + lr[j] * ar - li[j] * ai;
      float ni2 = b2f(ii[j]) + lr[j] * ai + li[j] * ar;
      sr[j] = nr2; si[j] = ni2;
      orr[j] = f2b(nr2); oii[j] = f2b(ni2);
    }
    *(ushort4*)p        = *(ushort4*)orr;
    *(ushort4*)(p + H_) = *(ushort4*)oii;
    p += 2 * H_;
    cre = nre; cim = nim;
  }
#pragma unroll
  for (int j = 0; j < 4; ++j)
    segfin[(size_t)(b * SEG_ + s) * H_ + c4 + j] = make_float2(sr[j], si[j]);
  if (threadIdx.x == 0) prodm[b * SEG_ + s] = pm;
}

// ---------------------------------------------------------------------------
// Scan pass 2: carries across segments. carry_{s+1} = fin_s + carry_s *
// (lambda^T * prod_mask_s); lambda^T in closed form exp(-nu*T + i*theta*T).
// ---------------------------------------------------------------------------
__global__ __launch_bounds__(256) void scan_carry(
    const float2* __restrict__ segfin, const float* __restrict__ prodm,
    const float* __restrict__ params, float2* __restrict__ carries)
{
  int idx = blockIdx.x * 256 + threadIdx.x;   // 0..8191
  int b = idx >> 10, c = idx & 1023;
  float nu = expf(params[c]);
  float th = expf(params[H_ + c]);
  float mg = expf(-nu * (float)T_);
  float ltr = mg * cosf(th * (float)T_);
  float lti = mg * sinf(th * (float)T_);
  float cr = 0.f, ci = 0.f;
  for (int s = 0; s < SEG_; ++s) {
    size_t o = (size_t)(b * SEG_ + s) * H_ + c;
    carries[o] = make_float2(cr, ci);
    float2 fin = segfin[o];
    float pmv = prodm[b * SEG_ + s];
    float nr = fin.x + pmv * (ltr * cr - lti * ci);
    float ni = fin.y + pmv * (ltr * ci + lti * cr);
    cr = nr; ci = ni;
  }
}

// ---------------------------------------------------------------------------
// Scan pass 3: add carry contribution. coef <- coef*lambda*m[t-1]; h[t]+=coef.
// Segments s>=1 only (carry_0 = 0).
// ---------------------------------------------------------------------------
__global__ __launch_bounds__(256) void scan_apply(
    u16* __restrict__ h, const float* __restrict__ mask,
    const float* __restrict__ params, const float2* __restrict__ carries)
{
  const int s = blockIdx.x + 1, b = blockIdx.y;
  const int c4 = threadIdx.x * 4;
  float lr[4], li[4], cr[4], ci[4];
#pragma unroll
  for (int j = 0; j < 4; ++j) {
    int c = c4 + j;
    float nu = expf(params[c]);
    float th = expf(params[H_ + c]);
    float mg = expf(-nu);
    lr[j] = mg * cosf(th);
    li[j] = mg * sinf(th);
    float2 cv = carries[(size_t)(b * SEG_ + s) * H_ + c];
    cr[j] = cv.x; ci[j] = cv.y;
  }
  const int t0 = s * T_;
  u16* p = h + (size_t)(b * L_ + t0) * (2 * H_) + c4;
  const float* mp = mask + b * L_ + t0;
  for (int i = 0; i < T_; ++i) {
    float fac = mp[i - 1];                // t0 >= 64, always valid
    u16 rr[4], ii[4], orr[4], oii[4];
    *(ushort4*)rr = *(const ushort4*)p;
    *(ushort4*)ii = *(const ushort4*)(p + H_);
#pragma unroll
    for (int j = 0; j < 4; ++j) {
      float nr2 = fac * (lr[j] * cr[j] - li[j] * ci[j]);
      float ni2 = fac * (lr[j] * ci[j] + li[j] * cr[j]);
      cr[j] = nr2; ci[j] = ni2;
      orr[j] = f2b(b2f(rr[j]) + nr2);
      oii[j] = f2b(b2f(ii[j]) + ni2);
    }
    *(ushort4*)p        = *(ushort4*)orr;
    *(ushort4*)(p + H_) = *(ushort4*)oii;
    p += 2 * H_;
  }
}

// ---------------------------------------------------------------------------
// LayerNorm: z = y + x; out = (z-mean)/sqrt(var+eps)*w + b.  One wave per
// 512-wide row (8 elems/lane), 64-lane shuffle reduction, 4 rows per block.
// All fp32.
// ---------------------------------------------------------------------------
__global__ __launch_bounds__(256) void ln_kernel(
    const float* __restrict__ y, const float* __restrict__ xg,
    const float* __restrict__ lnw, const float* __restrict__ lnb,
    float* __restrict__ out)
{
  const int wave = threadIdx.x >> 6, lane = threadIdx.x & 63;
  const size_t row = (size_t)blockIdx.x * 4 + wave;
  const float* yr = y + row * 512;
  const float* xr = xg + row * 512;
  float z[8];
  { float4 t = *(const float4*)&yr[lane * 4];        z[0]=t.x; z[1]=t.y; z[2]=t.z; z[3]=t.w; }
  { float4 t = *(const float4*)&yr[256 + lane * 4];  z[4]=t.x; z[5]=t.y; z[6]=t.z; z[7]=t.w; }
  { float4 t = *(const float4*)&xr[lane * 4];        z[0]+=t.x; z[1]+=t.y; z[2]+=t.z; z[3]+=t.w; }
  { float4 t = *(const float4*)&xr[256 + lane * 4];  z[4]+=t.x; z[5]+=t.y; z[6]+=t.z; z[7]+=t.w; }
  float s = 0.f, ss = 0.f;
#pragma unroll
  for (int j = 0; j < 8; ++j) { s += z[j]; ss += z[j] * z[j]; }
#pragma unroll
  for (int o = 32; o > 0; o >>= 1) { s += __shfl_xor(s, o); ss += __shfl_xor(ss, o); }
  const float mean = s * (1.f / 512.f);
  const float var  = ss * (1.f / 512.f) - mean * mean;
  const float inv  = rsqrtf(var + 1e-5f);
  float ov[8];
#pragma unroll
  for (int j = 0; j < 8; ++j) {
    int col = (j < 4) ? (lane * 4 + j) : (256 + lane * 4 + (j - 4));
    ov[j] = (z[j] - mean) * inv * lnw[col] + lnb[col];
  }
  { float4 t; t.x=ov[0]; t.y=ov[1]; t.z=ov[2]; t.w=ov[3];
    *(float4*)&out[row * 512 + lane * 4] = t; }
  { float4 t; t.x=ov[4]; t.y=ov[5]; t.z=ov[6]; t.w=ov[7];
    *(float4*)&out[row * 512 + 256 + lane * 4] = t; }
}

// ---------------------------------------------------------------------------
extern "C" void kernel_launch(void* const* d_in, const int* in_sizes, int n_in,
                              void* d_out, int out_size, void* d_ws, size_t ws_size,
                              hipStream_t stream) {
  (void)in_sizes; (void)n_in; (void)out_size; (void)ws_size;
  const float* x      = (const float*)d_in[0];
  const float* mask   = (const float*)d_in[1];
  const float* params = (const float*)d_in[2];   // [3][1024]: nu_log, theta_log, gamma_log
  const float* Wire   = (const float*)d_in[3];
  const float* Wiim   = (const float*)d_in[4];
  const float* bire   = (const float*)d_in[5];
  const float* biim   = (const float*)d_in[6];
  const float* Wore   = (const float*)d_in[7];
  const float* Woim   = (const float*)d_in[8];
  const float* bore   = (const float*)d_in[9];
  // d_in[10] = b_out_im: only affects Im(y), discarded by .real
  const float* lnw    = (const float*)d_in[11];
  const float* lnb    = (const float*)d_in[12];

  // workspace layout (~109 MB). xb (16.8 MB) unions with y (33.5 MB):
  // xb is dead after gemm1; y is written by gemm2 afterwards.
  char* ws = (char*)d_ws;
  float*  y       = (float*) (ws);                         // 16384*512*4  = 33,554,432
  u16*    xb      = (u16*)   (ws);                         // 16384*512*2  (union w/ y)
  u16*    h       = (u16*)   (ws + (size_t)33554432);      // 16384*2048*2 = 67,108,864
  u16*    winb    = (u16*)   (ws + (size_t)100663296);     // 2048*512*2   =  2,097,152
  u16*    wcat    = (u16*)   (ws + (size_t)102760448);     // 512*2048*2   =  2,097,152
  float2* segfin  = (float2*)(ws + (size_t)104857600);     // 8*32*1024*8  =  2,097,152
  float2* carries = (float2*)(ws + (size_t)106954752);     //              =  2,097,152
  float*  prodm   = (float*) (ws + (size_t)109051904);     // 256*4

  // fp32 -> bf16 conversions
  conv_f32_bf16<<<8192, 256, 0, stream>>>(x, xb, M_ * D_ / 4);          // 2.1M float4
  conv_f32_bf16<<<512, 256, 0, stream>>>(Wire, winb, H_ * D_ / 4);      // rows 0..1023
  conv_f32_bf16<<<512, 256, 0, stream>>>(Wiim, winb + H_ * D_, H_ * D_ / 4); // rows 1024..
  prep_wcat<<<2048, 256, 0, stream>>>(Wore, Woim, wcat);

  // h[re|im] = (x @ [W_in_re;W_in_im]^T + b_in)*gamma  (M=16384,N=2048,K=512)
  gemm_bt<0><<<dim3(16, 128), 256, 0, stream>>>(
      xb, winb, 512, (void*)h, 2048, bire, biim, params);

  scan_local<<<dim3(SEG_, B_), 256, 0, stream>>>(h, mask, params, segfin, prodm);
  scan_carry<<<32, 256, 0, stream>>>(segfin, prodm, params, carries);
  scan_apply<<<dim3(SEG_ - 1, B_), 256, 0, stream>>>(h, mask, params, carries);

  // y = h_cat @ Wcat^T + b_out_re   (M=16384,N=512,K=2048), fp32 out
  gemm_bt<1><<<dim3(4, 128), 256, 0, stream>>>(
      h, wcat, 2048, (void*)y, 512, bore, nullptr, nullptr);

  ln_kernel<<<4096, 256, 0, stream>>>(y, x, lnw, lnb, (float*)d_out);
}

// Round 3
// 262.477 us; speedup vs baseline: 1.1004x; 1.1004x over previous
//
#include <hip/hip_runtime.h>
#include <hip/hip_bf16.h>
#include <cstdint>
#include <cstddef>

// ---------------------------------------------------------------------------
// LRU layer (fp32 I/O): h = scan( (x W_in^T + b_in)*gamma, lambda, mask )
//                       out = LN( Re(h W_out^T + b_out) + x )
// B=8 L=2048 D=512 H=1024. GEMMs: bf16 MFMA, fp32 accum. Scan: fp32 state,
// bf16 h storage, fin/carry/full 3-pass (201 MB vs 264 MB for local+apply).
// ---------------------------------------------------------------------------

typedef unsigned short u16;
typedef __attribute__((ext_vector_type(8))) short bf16x8;   // 8 bf16 = 4 VGPRs
typedef __attribute__((ext_vector_type(4))) float f32x4;

#define B_    8
#define L_    2048
#define D_    512
#define H_    1024
#define M_    (B_ * L_)      // 16384 rows
#define SEG_  64             // scan segments (512 blocks = 2/CU)
#define T_    (L_ / SEG_)    // 32 steps/segment

__device__ __forceinline__ float b2f(u16 u) {
  union { unsigned int i; float f; } v; v.i = ((unsigned int)u) << 16; return v.f;
}
__device__ __forceinline__ u16 f2b(float f) {
  union { float f; unsigned int i; } v; v.f = f;
  unsigned int x = v.i;
  return (u16)((x + 0x7fffu + ((x >> 16) & 1u)) >> 16);   // RNE
}

// async global->LDS, 16B per lane. LDS dst must be uniform-base + lane*16.
__device__ __forceinline__ void gl2lds16(const void* g, void* l) {
  __builtin_amdgcn_global_load_lds(
      (const __attribute__((address_space(1))) void*)g,
      (__attribute__((address_space(3))) void*)l, 16, 0, 0);
}

// XOR swizzle of the 4 16B-chunks in a 32-wide K row: 2-way LDS aliasing max.
__device__ __forceinline__ int ksw(int row, int kc) {
  return (kc ^ (row & 3) ^ ((row >> 2) & 3)) & 3;
}

// ---------------------------------------------------------------------------
// fp32 -> bf16 elementwise, 4 elems/thread (n4 = n/4 float4 groups)
// ---------------------------------------------------------------------------
__global__ __launch_bounds__(256) void conv_f32_bf16(
    const float* __restrict__ in, u16* __restrict__ out, int n4)
{
  int i = blockIdx.x * 256 + threadIdx.x;
  if (i < n4) {
    float4 v = ((const float4*)in)[i];
    ushort4 o;
    o.x = f2b(v.x); o.y = f2b(v.y); o.z = f2b(v.z); o.w = f2b(v.w);
    ((ushort4*)out)[i] = o;
  }
}

// One-shot weight prep: winb = bf16([W_in_re; W_in_im])  (2048 x 512)
//                       wcat[d][c]=W_out_re[d][c], wcat[d][1024+c]=-W_out_im
__global__ __launch_bounds__(256) void prep_weights(
    const float* __restrict__ wire, const float* __restrict__ wiim,
    const float* __restrict__ wore, const float* __restrict__ woim,
    u16* __restrict__ winb, u16* __restrict__ wcat)
{
  int i = blockIdx.x * 256 + threadIdx.x;        // 0 .. 524287
  winb[i]                  = f2b(wire[i]);
  winb[H_ * D_ + i]        = f2b(wiim[i]);
  int d = i >> 10, c = i & 1023;
  wcat[(size_t)d * 2048 + c]        = f2b(wore[i]);
  wcat[(size_t)d * 2048 + 1024 + c] = f2b(-woim[i]);
}

// ---------------------------------------------------------------------------
// gemm_bt: C(M x N) = A(M x K) * B(N x K)^T, 128x128 tile, 4 waves 2x2,
// 16x16x32 bf16 MFMA, BK=32, global_load_lds staging (m97 structure).
// Grid: blockIdx.x = m-block (fast axis) so the n-blocks sharing an A-tile
// are 128 apart in flat index -> same XCD (flat%8) -> A fetched once per L2.
// MODE 0: out bf16; val=(acc + bias[n]) * exp(params[2048 + (n&1023)]).
// MODE 1: out fp32; val=acc + p0[n].
// ---------------------------------------------------------------------------
template <int MODE>
__global__ __launch_bounds__(256, 4) void gemm_bt(
    const u16* __restrict__ A, const u16* __restrict__ Bp, int K,
    void* __restrict__ outp, int ldc,
    const float* __restrict__ p0, const float* __restrict__ p1,
    const float* __restrict__ p2)
{
  __shared__ __align__(16) u16 sA[128 * 32];
  __shared__ __align__(16) u16 sB[128 * 32];

  const int tid  = threadIdx.x;
  const int lane = tid & 63;
  const int wave = tid >> 6;
  const int wm = wave >> 1, wn = wave & 1;           // 2x2 wave grid, 64x64 each
  const int m0 = blockIdx.x * 128;                   // m on fast axis (XCD share)
  const int n0 = blockIdx.y * 128;

  f32x4 acc[4][4];
#pragma unroll
  for (int i = 0; i < 4; ++i)
#pragma unroll
    for (int j = 0; j < 4; ++j) { f32x4 z = {0.f, 0.f, 0.f, 0.f}; acc[i][j] = z; }

  const int q = lane >> 4;       // quad 0..3 -> k-offset q*8
  const int r = lane & 15;       // m (A) / n (B) index within 16

  for (int k0 = 0; k0 < K; k0 += 32) {
#pragma unroll
    for (int it = 0; it < 2; ++it) {
      int ci  = it * 256 + tid;          // LDS slot; dst = uniform + lane*16
      int row = ci >> 2;
      int kc  = ksw(row, ci & 3);        // swizzled source chunk
      gl2lds16(A  + (size_t)(m0 + row) * K + k0 + kc * 8, &sA[ci * 8]);
      gl2lds16(Bp + (size_t)(n0 + row) * K + k0 + kc * 8, &sB[ci * 8]);
    }
    __syncthreads();

    bf16x8 af[4], bfv[4];
#pragma unroll
    for (int mt = 0; mt < 4; ++mt) {
      int arow = wm * 64 + mt * 16 + r;
      int slot = (arow << 2) | ksw(arow, q);
      af[mt] = *(const bf16x8*)&sA[slot * 8];
    }
#pragma unroll
    for (int nt = 0; nt < 4; ++nt) {
      int brow = wn * 64 + nt * 16 + r;
      int slot = (brow << 2) | ksw(brow, q);
      bfv[nt] = *(const bf16x8*)&sB[slot * 8];
    }
#pragma unroll
    for (int mt = 0; mt < 4; ++mt)
#pragma unroll
      for (int nt = 0; nt < 4; ++nt)
        acc[mt][nt] = __builtin_amdgcn_mfma_f32_16x16x32_bf16(
            af[mt], bfv[nt], acc[mt][nt], 0, 0, 0);
    __syncthreads();
  }

  // epilogue. D layout (m89-verified): col=lane&15 (n), row=q*4+i (m)
#pragma unroll
  for (int nt = 0; nt < 4; ++nt) {
    const int ng = n0 + wn * 64 + nt * 16 + r;
    float bias, gam = 1.f;
    if (MODE == 0) {
      bias = (ng < 1024) ? p0[ng] : p1[ng - 1024];
      gam  = expf(p2[2 * H_ + (ng & (H_ - 1))]);   // gamma = exp(gamma_log)
    } else {
      bias = p0[ng];
    }
#pragma unroll
    for (int mt = 0; mt < 4; ++mt) {
      const int mg = m0 + wm * 64 + mt * 16 + q * 4;
#pragma unroll
      for (int i = 0; i < 4; ++i) {
        float v = acc[mt][nt][i] + bias;
        if (MODE == 0)
          ((u16*)outp)[(size_t)(mg + i) * ldc + ng] = f2b(v * gam);
        else
          ((float*)outp)[(size_t)(mg + i) * ldc + ng] = v;
      }
    }
  }
}

// ---------------------------------------------------------------------------
// Scan pass 1 (read-only): segment-final state with zero init + mask product.
// 8-row chunks of independent loads (double-buffered) -> streams at BW.
// h_t = x_t + lambda * m[t-1] * h_{t-1}.
// ---------------------------------------------------------------------------
__global__ __launch_bounds__(256) void scan_fin(
    const u16* __restrict__ h, const float* __restrict__ mask,
    const float* __restrict__ params, float2* __restrict__ segfin,
    float* __restrict__ prodm)
{
  const int s = blockIdx.x, b = blockIdx.y;
  const int c4 = threadIdx.x * 4;
  float lr[4], li[4];
#pragma unroll
  for (int j = 0; j < 4; ++j) {
    int c = c4 + j;
    float nu = expf(params[c]);
    float th = expf(params[H_ + c]);
    float mg = expf(-nu);
    lr[j] = mg * cosf(th);
    li[j] = mg * sinf(th);
  }
  const int t0 = s * T_;
  const u16* p = h + (size_t)(b * L_ + t0) * (2 * H_) + c4;
  const float* mp = mask + b * L_ + t0;
  float fac0;                 // block-uniform branch: no OOB speculative load
  if (t0 == 0) fac0 = 0.f; else fac0 = mask[b * L_ + t0 - 1];

  ushort4 bre[2][8], bim[2][8];
#pragma unroll
  for (int j = 0; j < 8; ++j) {
    bre[0][j] = *(const ushort4*)(p + (size_t)j * 2 * H_);
    bim[0][j] = *(const ushort4*)(p + (size_t)j * 2 * H_ + H_);
  }
  float sr[4] = {0, 0, 0, 0}, si[4] = {0, 0, 0, 0};
  float pm = 1.f;
#pragma unroll
  for (int ch = 0; ch < T_ / 8; ++ch) {
    const int cur = ch & 1, nxt = cur ^ 1;
    if (ch < T_ / 8 - 1) {
      const u16* pn = p + (size_t)(ch + 1) * 8 * 2 * H_;
#pragma unroll
      for (int j = 0; j < 8; ++j) {
        bre[nxt][j] = *(const ushort4*)(pn + (size_t)j * 2 * H_);
        bim[nxt][j] = *(const ushort4*)(pn + (size_t)j * 2 * H_ + H_);
      }
    }
#pragma unroll
    for (int j = 0; j < 8; ++j) {
      int i = ch * 8 + j;
      float fac = (i == 0) ? fac0 : mp[i - 1];
      pm *= fac;
      u16 rr[4], ii[4];
      *(ushort4*)rr = bre[cur][j]; *(ushort4*)ii = bim[cur][j];
#pragma unroll
      for (int k = 0; k < 4; ++k) {
        float ar = fac * sr[k], ai = fac * si[k];
        sr[k] = b2f(rr[k]) + lr[k] * ar - li[k] * ai;
        si[k] = b2f(ii[k]) + lr[k] * ai + li[k] * ar;
      }
    }
  }
#pragma unroll
  for (int j = 0; j < 4; ++j)
    segfin[(size_t)(b * SEG_ + s) * H_ + c4 + j] = make_float2(sr[j], si[j]);
  if (threadIdx.x == 0) prodm[b * SEG_ + s] = pm;
}

// ---------------------------------------------------------------------------
// Scan pass 2: carries[s] = h-state entering segment s.
// carry_{s+1} = fin_s + prodm_s * lambda^T * carry_s.  lambda^T by 5 complex
// squarings (T=32) — avoids large-angle trig.
// ---------------------------------------------------------------------------
__global__ __launch_bounds__(256) void scan_carry(
    const float2* __restrict__ segfin, const float* __restrict__ prodm,
    const float* __restrict__ params, float2* __restrict__ carries)
{
  int idx = blockIdx.x * 256 + threadIdx.x;   // 0..8191
  int b = idx >> 10, c = idx & 1023;
  float nu = expf(params[c]);
  float th = expf(params[H_ + c]);
  float mg = expf(-nu);
  float ltr = mg * cosf(th), lti = mg * sinf(th);
#pragma unroll
  for (int sq = 0; sq < 5; ++sq) {            // lambda^(2^5) = lambda^T, T=32
    float nr = ltr * ltr - lti * lti;
    float ni = 2.f * ltr * lti;
    ltr = nr; lti = ni;
  }
  float cr = 0.f, ci = 0.f;
  for (int s = 0; s < SEG_; ++s) {
    size_t o = (size_t)(b * SEG_ + s) * H_ + c;
    carries[o] = make_float2(cr, ci);
    float2 fin = segfin[o];
    float pmv = prodm[b * SEG_ + s];
    float nr = fin.x + pmv * (ltr * cr - lti * ci);
    float ni = fin.y + pmv * (ltr * ci + lti * cr);
    cr = nr; ci = ni;
  }
}

// ---------------------------------------------------------------------------
// Scan pass 3: full scan with injected carry, single h rewrite.
// ---------------------------------------------------------------------------
__global__ __launch_bounds__(256) void scan_full(
    u16* __restrict__ h, const float* __restrict__ mask,
    const float* __restrict__ params, const float2* __restrict__ carries)
{
  const int s = blockIdx.x, b = blockIdx.y;
  const int c4 = threadIdx.x * 4;
  float lr[4], li[4], sr[4], si[4];
#pragma unroll
  for (int j = 0; j < 4; ++j) {
    int c = c4 + j;
    float nu = expf(params[c]);
    float th = expf(params[H_ + c]);
    float mg = expf(-nu);
    lr[j] = mg * cosf(th);
    li[j] = mg * sinf(th);
    float2 cv = carries[(size_t)(b * SEG_ + s) * H_ + c];
    sr[j] = cv.x; si[j] = cv.y;
  }
  const int t0 = s * T_;
  u16* p = h + (size_t)(b * L_ + t0) * (2 * H_) + c4;
  const float* mp = mask + b * L_ + t0;
  float fac0;
  if (t0 == 0) fac0 = 0.f; else fac0 = mask[b * L_ + t0 - 1];

  ushort4 cre = *(const ushort4*)p;
  ushort4 cim = *(const ushort4*)(p + H_);
  for (int i = 0; i < T_; ++i) {
    ushort4 nre = cre, nim = cim;
    if (i + 1 < T_) {                       // prefetch next row before store
      nre = *(const ushort4*)(p + 2 * H_);
      nim = *(const ushort4*)(p + 2 * H_ + H_);
    }
    float fac = (i == 0) ? fac0 : mp[i - 1];
    u16 rr[4], ii[4], orr[4], oii[4];
    *(ushort4*)rr = cre; *(ushort4*)ii = cim;
#pragma unroll
    for (int j = 0; j < 4; ++j) {
      float ar = fac * sr[j], ai = fac * si[j];
      float nr2 = b2f(rr[j]) + lr[j] * ar - li[j] * ai;
      float ni2 = b2f(ii[j]) + lr[j] * ai + li[j] * ar;
      sr[j] = nr2; si[j] = ni2;
      orr[j] = f2b(nr2); oii[j] = f2b(ni2);
    }
    *(ushort4*)p        = *(ushort4*)orr;
    *(ushort4*)(p + H_) = *(ushort4*)oii;
    p += 2 * H_;
    cre = nre; cim = nim;
  }
}

// ---------------------------------------------------------------------------
// LayerNorm: z = y + x; out = (z-mean)/sqrt(var+eps)*w + b.  One wave per
// 512-wide row (8 elems/lane), 64-lane shuffle reduction, 4 rows per block.
// ---------------------------------------------------------------------------
__global__ __launch_bounds__(256) void ln_kernel(
    const float* __restrict__ y, const float* __restrict__ xg,
    const float* __restrict__ lnw, const float* __restrict__ lnb,
    float* __restrict__ out)
{
  const int wave = threadIdx.x >> 6, lane = threadIdx.x & 63;
  const size_t row = (size_t)blockIdx.x * 4 + wave;
  const float* yr = y + row * 512;
  const float* xr = xg + row * 512;
  float z[8];
  { float4 t = *(const float4*)&yr[lane * 4];        z[0]=t.x; z[1]=t.y; z[2]=t.z; z[3]=t.w; }
  { float4 t = *(const float4*)&yr[256 + lane * 4];  z[4]=t.x; z[5]=t.y; z[6]=t.z; z[7]=t.w; }
  { float4 t = *(const float4*)&xr[lane * 4];        z[0]+=t.x; z[1]+=t.y; z[2]+=t.z; z[3]+=t.w; }
  { float4 t = *(const float4*)&xr[256 + lane * 4];  z[4]+=t.x; z[5]+=t.y; z[6]+=t.z; z[7]+=t.w; }
  float s = 0.f, ss = 0.f;
#pragma unroll
  for (int j = 0; j < 8; ++j) { s += z[j]; ss += z[j] * z[j]; }
#pragma unroll
  for (int o = 32; o > 0; o >>= 1) { s += __shfl_xor(s, o); ss += __shfl_xor(ss, o); }
  const float mean = s * (1.f / 512.f);
  const float var  = ss * (1.f / 512.f) - mean * mean;
  const float inv  = rsqrtf(var + 1e-5f);
  float ov[8];
#pragma unroll
  for (int j = 0; j < 8; ++j) {
    int col = (j < 4) ? (lane * 4 + j) : (256 + lane * 4 + (j - 4));
    ov[j] = (z[j] - mean) * inv * lnw[col] + lnb[col];
  }
  { float4 t; t.x=ov[0]; t.y=ov[1]; t.z=ov[2]; t.w=ov[3];
    *(float4*)&out[row * 512 + lane * 4] = t; }
  { float4 t; t.x=ov[4]; t.y=ov[5]; t.z=ov[6]; t.w=ov[7];
    *(float4*)&out[row * 512 + 256 + lane * 4] = t; }
}

// ---------------------------------------------------------------------------
extern "C" void kernel_launch(void* const* d_in, const int* in_sizes, int n_in,
                              void* d_out, int out_size, void* d_ws, size_t ws_size,
                              hipStream_t stream) {
  (void)in_sizes; (void)n_in; (void)out_size; (void)ws_size;
  const float* x      = (const float*)d_in[0];
  const float* mask   = (const float*)d_in[1];
  const float* params = (const float*)d_in[2];   // [3][1024]: nu_log, theta_log, gamma_log
  const float* Wire   = (const float*)d_in[3];
  const float* Wiim   = (const float*)d_in[4];
  const float* bire   = (const float*)d_in[5];
  const float* biim   = (const float*)d_in[6];
  const float* Wore   = (const float*)d_in[7];
  const float* Woim   = (const float*)d_in[8];
  const float* bore   = (const float*)d_in[9];
  // d_in[10] = b_out_im: only affects Im(y), discarded by .real
  const float* lnw    = (const float*)d_in[11];
  const float* lnb    = (const float*)d_in[12];

  // Workspace (~105 MB). Region [0, 33.5M) is time-shared:
  //   xb (gemm1 input) -> segfin/carries/prodm (scan phase) -> y (gemm2/ln).
  char* ws = (char*)d_ws;
  u16*    xb      = (u16*)   (ws);                         // 16384*512*2
  float2* segfin  = (float2*)(ws);                         // 8*64*1024*8 = 4 MB
  float2* carries = (float2*)(ws + (size_t)4194304);       // 4 MB
  float*  prodm   = (float*) (ws + (size_t)8388608);       // 2 KB
  float*  y       = (float*) (ws);                         // 16384*512*4 = 33.5 MB
  u16*    h       = (u16*)   (ws + (size_t)33554432);      // 16384*2048*2 = 67 MB
  u16*    winb    = (u16*)   (ws + (size_t)100663296);     // 2048*512*2 = 2 MB
  u16*    wcat    = (u16*)   (ws + (size_t)102760448);     // 512*2048*2 = 2 MB

  conv_f32_bf16<<<8192, 256, 0, stream>>>(x, xb, M_ * D_ / 4);
  prep_weights<<<2048, 256, 0, stream>>>(Wire, Wiim, Wore, Woim, winb, wcat);

  // h[re|im] = (x @ [W_in_re;W_in_im]^T + b_in)*gamma  (M=16384,N=2048,K=512)
  gemm_bt<0><<<dim3(128, 16), 256, 0, stream>>>(
      xb, winb, 512, (void*)h, 2048, bire, biim, params);

  scan_fin<<<dim3(SEG_, B_), 256, 0, stream>>>(h, mask, params, segfin, prodm);
  scan_carry<<<32, 256, 0, stream>>>(segfin, prodm, params, carries);
  scan_full<<<dim3(SEG_, B_), 256, 0, stream>>>(h, mask, params, carries);

  // y = h_cat @ Wcat^T + b_out_re   (M=16384,N=512,K=2048), fp32 out
  gemm_bt<1><<<dim3(128, 4), 256, 0, stream>>>(
      h, wcat, 2048, (void*)y, 512, bore, nullptr, nullptr);

  ln_kernel<<<4096, 256, 0, stream>>>(y, x, lnw, lnb, (float*)d_out);
}